// Round 11
// baseline (407.574 us; speedup 1.0000x reference)
//
#include <hip/hip_runtime.h>

// ChebNet round 11: slim CSR build (packed 4B edges, fused hist+scan via
// last-block pattern, register-replay local sort), 8-group 16B-load prop.
// MFMA GEMMs unchanged from R10.

typedef unsigned short ushort_t;
typedef __attribute__((ext_vector_type(8))) short v8s;
typedef __attribute__((ext_vector_type(8))) unsigned short u8s;
typedef __attribute__((ext_vector_type(4))) float v4f;

__device__ inline ushort_t f2bf(float f) {  // RNE float->bf16
    unsigned u = __float_as_uint(f);
    return (ushort_t)((u + 0x7FFFu + ((u >> 16) & 1u)) >> 16);
}
__device__ inline float bf2f(ushort_t h) {
    return __uint_as_float(((unsigned)h) << 16);
}

#define BSH 9
#define BSZ (1 << BSH)
#define CHUNK 4096

// ---------- stage 1: bucket histogram + (last block) exclusive scan ----------
__global__ __launch_bounds__(256) void k_bhist(
    const int* __restrict__ dst, int* __restrict__ gbase, int* __restrict__ gcur,
    int* __restrict__ done, int E, int NB) {
    __shared__ int h[256];
    __shared__ int sc[256];
    __shared__ int isLast;
    int t = threadIdx.x;
    h[t] = 0;
    __syncthreads();
    for (int i = blockIdx.x * 256 + t; i < E; i += gridDim.x * 256)
        atomicAdd(&h[dst[i] >> BSH], 1);
    __syncthreads();
    if (t < NB && h[t]) atomicAdd(&gbase[t], h[t]);
    __threadfence();
    if (t == 0) isLast = (atomicAdd(done, 1) == (int)gridDim.x - 1);
    __syncthreads();
    if (!isLast) return;
    // exclusive scan of gbase[0..NB) (coherent reads via atomic)
    int v = (t < NB) ? atomicAdd(&gbase[t], 0) : 0;
    sc[t] = v;
    __syncthreads();
    for (int off = 1; off < 256; off <<= 1) {
        int u = 0;
        if (t >= off) u = sc[t - off];
        __syncthreads();
        sc[t] += u;
        __syncthreads();
    }
    if (t < NB) {
        int excl = sc[t] - v;
        gbase[t] = excl;
        gcur[t] = excl;
    }
}

// ---------- stage 2: scatter packed edges into bucket regions ----------
__global__ __launch_bounds__(256) void k_bucket2(
    const int* __restrict__ src, const int* __restrict__ dst,
    int* __restrict__ gcur, int* __restrict__ eb, int E, int NB) {
    __shared__ int lv[CHUNK];
    __shared__ unsigned char lb[CHUNK];
    __shared__ int hist[256];
    __shared__ int bbase[256];
    int t = threadIdx.x;
    int base = blockIdx.x * CHUNK;
    int count = E - base;
    if (count > CHUNK) count = CHUNK;
    hist[t] = 0;
    __syncthreads();
    for (int i = t; i < count; i += 256) {
        int s = src[base + i];
        int d = dst[base + i];
        int b = d >> BSH;
        lv[i] = (s << BSH) | (d & (BSZ - 1));
        lb[i] = (unsigned char)b;
        atomicAdd(&hist[b], 1);
    }
    __syncthreads();
    {
        int c = hist[t];
        bbase[t] = (t < NB && c) ? atomicAdd(&gcur[t], c) : 0;
        hist[t] = 0;  // reuse as local cursor
    }
    __syncthreads();
    for (int i = t; i < count; i += 256) {
        int b = lb[i];
        int off = atomicAdd(&hist[b], 1);
        eb[bbase[b] + off] = lv[i];
    }
}

// ---------- stage 3: per-bucket finalize (register replay) ----------
__global__ __launch_bounds__(256) void k_local(
    const int* __restrict__ eb, const int* __restrict__ gbase,
    int* __restrict__ col, int* __restrict__ row_ptr,
    float* __restrict__ dinv, int N, int E, int NB) {
    __shared__ int cnt[BSZ];
    __shared__ int tsum[256];
    int t = threadIdx.x;
    int b = blockIdx.x;
    int d0 = b << BSH;
    cnt[2 * t] = 0;
    cnt[2 * t + 1] = 0;
    __syncthreads();
    int beg = gbase[b];
    int end = (b + 1 < NB) ? gbase[b + 1] : E;
    int le[24];
    {
        int k = 0;
        for (int i = beg + t; i < end; i += 256, k++) {
            int v = eb[i];
            if (k < 24) le[k] = v;
            atomicAdd(&cnt[v & (BSZ - 1)], 1);
        }
    }
    __syncthreads();
    int c0 = cnt[2 * t], c1 = cnt[2 * t + 1];
    int mysum = c0 + c1;
    tsum[t] = mysum;
    __syncthreads();
    for (int off = 1; off < 256; off <<= 1) {
        int u = 0;
        if (t >= off) u = tsum[t - off];
        __syncthreads();
        tsum[t] += u;
        __syncthreads();
    }
    int rbase = beg + tsum[t] - mysum;
    int d = d0 + 2 * t;
    if (d < N) {
        row_ptr[d] = rbase;
        dinv[d] = rsqrtf(fmaxf((float)c0, 1.0f));
    }
    if (d + 1 < N) {
        row_ptr[d + 1] = rbase + c0;
        dinv[d + 1] = rsqrtf(fmaxf((float)c1, 1.0f));
    }
    cnt[2 * t] = rbase;
    cnt[2 * t + 1] = rbase + c0;
    __syncthreads();
    {
        int k = 0;
        for (int i = beg + t; i < end; i += 256, k++) {
            int v = (k < 24) ? le[k] : eb[i];
            int p = atomicAdd(&cnt[v & (BSZ - 1)], 1);
            col[p] = v >> BSH;
        }
    }
    if (b == NB - 1 && t == 0) row_ptr[N] = E;
}

// ---------- weight prep: fp32 -> bf16 transposed ----------
__global__ void k_wprep(const float* __restrict__ W1, const float* __restrict__ W2,
                        const float* __restrict__ Wm1, const float* __restrict__ Wm2,
                        ushort_t* __restrict__ W1t, ushort_t* __restrict__ W2t,
                        ushort_t* __restrict__ Wm1t, ushort_t* __restrict__ Wm2t) {
    int i = blockIdx.x * 256 + threadIdx.x;
    if (i < 12288) { int k = i >> 6, n = i & 63; W1t[n * 192 + k] = f2bf(W1[i]); return; }
    i -= 12288;
    if (i < 12288) { int k = i >> 6, n = i & 63; W2t[n * 192 + k] = f2bf(W2[i]); return; }
    i -= 12288;
    if (i < 4096) { int k = i >> 6, n = i & 63; Wm1t[n * 64 + k] = f2bf(Wm1[i]); return; }
    i -= 4096;
    if (i < 2048) { int k = i >> 5, n = i & 31; Wm2t[n * 64 + k] = f2bf(Wm2[i]); }
}

// ---------- fp32 -> scaled bf16 shadow ----------
__global__ void k_tobf16(const float4* __restrict__ X, const float* __restrict__ dinv,
                         ushort4* __restrict__ Y, int n4) {
    int i = blockIdx.x * blockDim.x + threadIdx.x;
    if (i < n4) {
        float s = dinv[i >> 4];
        float4 v = X[i];
        ushort4 o;
        o.x = f2bf(v.x * s); o.y = f2bf(v.y * s); o.z = f2bf(v.z * s); o.w = f2bf(v.w * s);
        Y[i] = o;
    }
}

// ---------- propagation: 8 groups x 8 lanes x 16B loads ----------
// MODE 1: OUTB = bf16(-di*di*S); MODE 2: OUTB = bf16(-2*di*S - X0/di)
template <int MODE>
__global__ __launch_bounds__(256) void k_prop(
    const ushort_t* __restrict__ Xb, const int* __restrict__ rp,
    const int* __restrict__ col, const float* __restrict__ dinv,
    const ushort_t* __restrict__ X0b, ushort_t* __restrict__ OUTB, int N) {
    int wid = (blockIdx.x * blockDim.x + threadIdx.x) >> 6;
    int lane = threadIdx.x & 63;
    if (wid >= N) return;
    int g = lane >> 3;        // edge-group 0..7
    int fl = (lane & 7) * 8;  // feature base (ushorts)
    int beg = rp[wid], end = rp[wid + 1];
    float a0[8] = {0, 0, 0, 0, 0, 0, 0, 0};
    float a1[8] = {0, 0, 0, 0, 0, 0, 0, 0};
    int e = beg + g;
    for (; e + 8 < end; e += 16) {
        int s0 = col[e], s1 = col[e + 8];
        u8s u0 = *(const u8s*)&Xb[(size_t)s0 * 64 + fl];
        u8s u1 = *(const u8s*)&Xb[(size_t)s1 * 64 + fl];
#pragma unroll
        for (int j = 0; j < 8; j++) a0[j] += bf2f(u0[j]);
#pragma unroll
        for (int j = 0; j < 8; j++) a1[j] += bf2f(u1[j]);
    }
    if (e < end) {
        int s0 = col[e];
        u8s u0 = *(const u8s*)&Xb[(size_t)s0 * 64 + fl];
#pragma unroll
        for (int j = 0; j < 8; j++) a0[j] += bf2f(u0[j]);
    }
    float acc[8];
#pragma unroll
    for (int j = 0; j < 8; j++) acc[j] = a0[j] + a1[j];
#pragma unroll
    for (int st = 8; st < 64; st <<= 1)
#pragma unroll
        for (int j = 0; j < 8; j++) acc[j] += __shfl_xor(acc[j], st);
    if (g == 0) {
        float di = dinv[wid];
        u8s ob;
        if (MODE == 1) {
            float m = -di * di;
#pragma unroll
            for (int j = 0; j < 8; j++) ob[j] = f2bf(m * acc[j]);
        } else {
            u8s x0u = *(const u8s*)&X0b[(size_t)wid * 64 + fl];
            float m = -2.0f * di;
            float rd = 1.0f / di;
#pragma unroll
            for (int j = 0; j < 8; j++)
                ob[j] = f2bf(fmaf(m, acc[j], -rd * bf2f(x0u[j])));
        }
        *(u8s*)&OUTB[(size_t)wid * 64 + fl] = ob;
    }
}

// ---------- cheb linear via MFMA (R10) ----------
template <bool SCALE_OUT>
__global__ __launch_bounds__(256) void k_cheb_mfma(
    const ushort_t* __restrict__ X0, const ushort_t* __restrict__ X1,
    const ushort_t* __restrict__ X2, const float* __restrict__ dinv,
    const ushort_t* __restrict__ Wt, const float* __restrict__ b,
    ushort_t* __restrict__ Yb, int N) {
    int wave = threadIdx.x >> 6, lane = threadIdx.x & 63;
    int n16 = lane & 15, q = lane >> 4;
    int node0 = blockIdx.x * 64;
    int arow = node0 + wave * 16 + n16;
    const ushort_t* Xc[3] = {X0, X1, X2};

    v4f acc_s[4], acc_u[4];
#pragma unroll
    for (int t = 0; t < 4; t++) {
        acc_s[t] = (v4f){0.f, 0.f, 0.f, 0.f};
        acc_u[t] = (v4f){0.f, 0.f, 0.f, 0.f};
    }
#pragma unroll
    for (int ks = 0; ks < 6; ks++) {
        int c = ks >> 1;
        int kk = (ks & 1) * 32 + q * 8;
        v8s av = {0, 0, 0, 0, 0, 0, 0, 0};
        if (arow < N) av = *(const v8s*)&Xc[c][(size_t)arow * 64 + kk];
#pragma unroll
        for (int t = 0; t < 4; t++) {
            v8s bv = *(const v8s*)&Wt[(size_t)(t * 16 + n16) * 192 + ks * 32 + q * 8];
            if (c < 2)
                acc_s[t] = __builtin_amdgcn_mfma_f32_16x16x32_bf16(av, bv, acc_s[t], 0, 0, 0);
            else
                acc_u[t] = __builtin_amdgcn_mfma_f32_16x16x32_bf16(av, bv, acc_u[t], 0, 0, 0);
        }
    }
    int rbase = node0 + wave * 16 + q * 4;
#pragma unroll
    for (int r = 0; r < 4; r++) {
        int row = rbase + r;
        if (row < N) {
            float dv = dinv[row];
            float rd = 1.0f / dv;
            float s = SCALE_OUT ? dv : 1.0f;
#pragma unroll
            for (int t = 0; t < 4; t++) {
                float y = fmaf(rd, acc_s[t][r], acc_u[t][r]) + b[t * 16 + n16];
                y = fmaxf(y, 0.0f);
                Yb[(size_t)row * 64 + t * 16 + n16] = f2bf(s * y);
            }
        }
    }
}

// ---------- MLP head via MFMA (R10) ----------
__global__ __launch_bounds__(256) void k_mlp_mfma(
    const ushort_t* __restrict__ Hb, const ushort_t* __restrict__ W1t,
    const float* __restrict__ b1, const ushort_t* __restrict__ W2t,
    const float* __restrict__ b2, float* __restrict__ out, int N) {
    __shared__ ushort_t Hs[64][76];
    int wave = threadIdx.x >> 6, lane = threadIdx.x & 63;
    int n16 = lane & 15, q = lane >> 4;
    int node0 = blockIdx.x * 64;
    int arow = node0 + wave * 16 + n16;

    v4f acc[4];
#pragma unroll
    for (int t = 0; t < 4; t++) acc[t] = (v4f){0.f, 0.f, 0.f, 0.f};
#pragma unroll
    for (int ks = 0; ks < 2; ks++) {
        v8s av = {0, 0, 0, 0, 0, 0, 0, 0};
        if (arow < N) av = *(const v8s*)&Hb[(size_t)arow * 64 + ks * 32 + q * 8];
#pragma unroll
        for (int t = 0; t < 4; t++) {
            v8s bv = *(const v8s*)&W1t[(size_t)(t * 16 + n16) * 64 + ks * 32 + q * 8];
            acc[t] = __builtin_amdgcn_mfma_f32_16x16x32_bf16(av, bv, acc[t], 0, 0, 0);
        }
    }
    int lr = wave * 16 + q * 4;
#pragma unroll
    for (int r = 0; r < 4; r++)
#pragma unroll
        for (int t = 0; t < 4; t++) {
            float y = acc[t][r] + b1[t * 16 + n16];
            Hs[lr + r][t * 16 + n16] = f2bf(fmaxf(y, 0.0f));
        }
    __syncthreads();

    v4f a2[2];
    a2[0] = (v4f){0.f, 0.f, 0.f, 0.f};
    a2[1] = (v4f){0.f, 0.f, 0.f, 0.f};
#pragma unroll
    for (int ks = 0; ks < 2; ks++) {
        v8s av = *(const v8s*)&Hs[wave * 16 + n16][ks * 32 + q * 8];
#pragma unroll
        for (int t = 0; t < 2; t++) {
            v8s bv = *(const v8s*)&W2t[(size_t)(t * 16 + n16) * 64 + ks * 32 + q * 8];
            a2[t] = __builtin_amdgcn_mfma_f32_16x16x32_bf16(av, bv, a2[t], 0, 0, 0);
        }
    }
    int rbase = node0 + wave * 16 + q * 4;
#pragma unroll
    for (int r = 0; r < 4; r++) {
        int row = rbase + r;
        if (row < N) {
#pragma unroll
            for (int t = 0; t < 2; t++)
                out[(size_t)row * 32 + t * 16 + n16] = a2[t][r] + b2[t * 16 + n16];
        }
    }
}

extern "C" void kernel_launch(void* const* d_in, const int* in_sizes, int n_in,
                              void* d_out, int out_size, void* d_ws, size_t ws_size,
                              hipStream_t stream) {
    const float* features = (const float*)d_in[0];
    const int* src = (const int*)d_in[1];
    const int* dst = (const int*)d_in[2];
    const float* W1 = (const float*)d_in[4];
    const float* b1 = (const float*)d_in[5];
    const float* W2 = (const float*)d_in[6];
    const float* b2 = (const float*)d_in[7];
    const float* Wm1 = (const float*)d_in[8];
    const float* bm1 = (const float*)d_in[9];
    const float* Wm2 = (const float*)d_in[10];
    const float* bm2 = (const float*)d_in[11];
    float* out = (float*)d_out;

    int N = in_sizes[0] / 64;
    int E = in_sizes[1];
    int NB = (N + BSZ - 1) >> BSH;  // 512-node dst buckets

    float* ws = (float*)d_ws;
    float* dinv = ws;                           // [N]
    int* row_ptr = (int*)(dinv + N);            // [N+1]
    int* gbase = row_ptr + (N + 1);             // [256]
    int* gcur = gbase + 256;                    // [256]
    int* done = gcur + 256;                     // [1]
    int* col = done + 1;                        // [E]
    int* eb = col + E;                          // [E] packed
    ushort_t* Fb  = (ushort_t*)(eb + E);        // [N*64] scaled
    ushort_t* X1b = Fb  + (size_t)N * 64;
    ushort_t* X2b = X1b + (size_t)N * 64;
    ushort_t* H1b = X2b + (size_t)N * 64;
    ushort_t* H2b = H1b + (size_t)N * 64;
    ushort_t* W1t = H2b + (size_t)N * 64;       // [64*192]
    ushort_t* W2t = W1t + 64 * 192;
    ushort_t* Wm1t = W2t + 64 * 192;            // [64*64]
    ushort_t* Wm2t = Wm1t + 64 * 64;            // [32*64]

    int pblk = (N * 64 + 255) / 256;
    int gblk = (N + 63) / 64;
    int n4 = N * 16;
    int cblk = (n4 + 255) / 256;
    int bblk = (E + CHUNK - 1) / CHUNK;

    // weight prep + CSR control zero
    k_wprep<<<(30720 + 255) / 256, 256, 0, stream>>>(W1, W2, Wm1, Wm2, W1t, W2t, Wm1t, Wm2t);
    hipMemsetAsync(gbase, 0, 513 * sizeof(int), stream);

    // CSR build
    k_bhist<<<256, 256, 0, stream>>>(dst, gbase, gcur, done, E, NB);
    k_bucket2<<<bblk, 256, 0, stream>>>(src, dst, gcur, eb, E, NB);
    k_local<<<NB, 256, 0, stream>>>(eb, gbase, col, row_ptr, dinv, N, E, NB);

    // scaled bf16 shadow of features
    k_tobf16<<<cblk, 256, 0, stream>>>((const float4*)features, dinv, (ushort4*)Fb, n4);

    // layer 1
    k_prop<1><<<pblk, 256, 0, stream>>>(Fb, row_ptr, col, dinv, nullptr, X1b, N);
    k_prop<2><<<pblk, 256, 0, stream>>>(X1b, row_ptr, col, dinv, Fb, X2b, N);
    k_cheb_mfma<true><<<gblk, 256, 0, stream>>>(Fb, X1b, X2b, dinv, W1t, b1, H1b, N);

    // layer 2
    k_prop<1><<<pblk, 256, 0, stream>>>(H1b, row_ptr, col, dinv, nullptr, X1b, N);
    k_prop<2><<<pblk, 256, 0, stream>>>(X1b, row_ptr, col, dinv, H1b, X2b, N);
    k_cheb_mfma<false><<<gblk, 256, 0, stream>>>(H1b, X1b, X2b, dinv, W2t, b2, H2b, N);

    // MLP head
    k_mlp_mfma<<<gblk, 256, 0, stream>>>(H2b, Wm1t, bm1, Wm2t, bm2, out, N);
}